// Round 1
// baseline (4038.592 us; speedup 1.0000x reference)
//
#include <hip/hip_runtime.h>
#include <stdint.h>

#define TOKENS 4096
#define DMODEL 2048
#define VOCAB  65536
#define IGNORE_IDX (-100)

#define BM 128
#define BN 128
#define BK 64
#define NSPLIT 32
#define NT_PER_SLICE (VOCAB / NSPLIT / BN)   /* 16 */
#define NPART (NSPLIT * 2)                   /* 64 partials per token */

typedef __bf16 bf16x8 __attribute__((ext_vector_type(8)));
typedef float  f32x4  __attribute__((ext_vector_type(4)));

__device__ __forceinline__ uint32_t f2bf_pack(float a, float b) {
  uint32_t ua = __float_as_uint(a), ub = __float_as_uint(b);
  ua = (ua + 0x7fffu + ((ua >> 16) & 1u)) >> 16;
  ub = (ub + 0x7fffu + ((ub >> 16) & 1u)) >> 16;
  return ua | (ub << 16);
}

// Targets are int64 in the reference; harness doc says int32. Sniff the layout:
// for int64 little-endian, every odd 32-bit word is 0 (or -1 for IGNORE).
__device__ __forceinline__ int tgt_mode64(const int* tg) {
  int a = tg[1], b = tg[3], c = tg[5];
  return (((a == 0) | (a == -1)) & ((b == 0) | (b == -1)) &
          ((c == 0) | (c == -1)));
}
__device__ __forceinline__ int load_tgt(const int* tg, int i, int m64) {
  return m64 ? tg[2 * i] : tg[i];
}

// ---------------------------------------------------------------- convert H
__global__ void k_convert(const float* __restrict__ H, uint32_t* __restrict__ Hb) {
  int tid = blockIdx.x * 256 + threadIdx.x;       // 131072 threads
  const float4* H4 = (const float4*)H;
  uint2* Hb2 = (uint2*)Hb;
#pragma unroll
  for (int i = 0; i < 16; ++i) {
    int idx = tid + i * 131072;                   // float4 index < 2097152
    float4 v = H4[idx];
    uint2 o;
    o.x = f2bf_pack(v.x, v.y);
    o.y = f2bf_pack(v.z, v.w);
    Hb2[idx] = o;
  }
}

// ---------------------------------------------------------------- target logit
__global__ void k_tgt(const float* __restrict__ H, const float* __restrict__ W,
                      const int* __restrict__ tg, float* __restrict__ tgt) {
  int w = threadIdx.x >> 6, lane = threadIdx.x & 63;
  int token = blockIdx.x * 4 + w;
  int m64 = tgt_mode64(tg);
  int t = load_tgt(tg, token, m64);
  float r = 0.f;
  if (t >= 0 && t < VOCAB) {
    const float4* h4 = (const float4*)(H + (size_t)token * DMODEL);
    const float4* w4 = (const float4*)(W + (size_t)t * DMODEL);
#pragma unroll
    for (int i = 0; i < 8; ++i) {
      float4 a = h4[i * 64 + lane], b = w4[i * 64 + lane];
      r += a.x * b.x + a.y * b.y + a.z * b.z + a.w * b.w;
    }
  }
#pragma unroll
  for (int d = 1; d < 64; d <<= 1) r += __shfl_xor(r, d, 64);
  if (lane == 0) tgt[token] = r;
}

// ---------------------------------------------------------------- main GEMM + online softmax stats
__global__ __launch_bounds__(256, 2) void k_gemm(
    const uint16_t* __restrict__ Hb, const float* __restrict__ W,
    float2* __restrict__ partials) {
  __shared__ uint4 ldsA[BM * BK / 8];   // 16 KB, swizzled 16B blocks
  __shared__ uint4 ldsB[BN * BK / 8];   // 16 KB
  char* baseA = (char*)ldsA;
  char* baseB = (char*)ldsB;

  const int tid = threadIdx.x;
  const int bid = blockIdx.x;
  const int mblk = bid & 31;            // 32 m-blocks (fast dim: same slice adjacent)
  const int slice = bid >> 5;           // 32 vocab slices
  const int wv = tid >> 6, lane = tid & 63;
  const int wm = wv >> 1, wn = wv & 1;
  const int lr = lane & 15, lg = lane >> 4;
  const int mrow0 = mblk * BM;

  int rowA[4], colB[4];
#pragma unroll
  for (int i = 0; i < 4; ++i) {
    rowA[i] = wm * 64 + i * 16 + lr;
    colB[i] = wn * 64 + i * 16 + lr;
  }

  float rmax[4][4], rsum[4][4];
#pragma unroll
  for (int a = 0; a < 4; ++a)
#pragma unroll
    for (int b = 0; b < 4; ++b) { rmax[a][b] = -INFINITY; rsum[a][b] = 0.f; }

  for (int nt = 0; nt < NT_PER_SLICE; ++nt) {
    const int vbase = slice * (NT_PER_SLICE * BN) + nt * BN;

    f32x4 acc[4][4];
#pragma unroll
    for (int a = 0; a < 4; ++a)
#pragma unroll
      for (int b = 0; b < 4; ++b) acc[a][b] = (f32x4){0.f, 0.f, 0.f, 0.f};

    for (int kt = 0; kt < DMODEL / BK; ++kt) {
      // ---- global loads into registers (before barrier: overlap w/ prev compute)
      uint4 aval[4];
#pragma unroll
      for (int i = 0; i < 4; ++i) {
        int bidx = i * 256 + tid;
        int arow = bidx >> 3, akb = bidx & 7;
        aval[i] = *(const uint4*)(Hb + (size_t)(mrow0 + arow) * DMODEL + kt * BK + akb * 8);
      }
      float4 bval[8];
#pragma unroll
      for (int i = 0; i < 8; ++i) {
        int f4 = i * 256 + tid;
        int brow = f4 >> 4, bk4 = f4 & 15;
        bval[i] = *(const float4*)(W + (size_t)(vbase + brow) * DMODEL + kt * BK + bk4 * 4);
      }
      __syncthreads();   // previous iteration's LDS reads done
      // ---- LDS writes (XOR-swizzled 16B blocks: blk ^= row&7)
#pragma unroll
      for (int i = 0; i < 4; ++i) {
        int bidx = i * 256 + tid;
        int arow = bidx >> 3, akb = bidx & 7;
        *(uint4*)(baseA + arow * 128 + ((akb ^ (arow & 7)) << 4)) = aval[i];
      }
#pragma unroll
      for (int i = 0; i < 8; ++i) {
        int f4 = i * 256 + tid;
        int brow = f4 >> 4, bk4 = f4 & 15;
        uint2 o;
        o.x = f2bf_pack(bval[i].x, bval[i].y);
        o.y = f2bf_pack(bval[i].z, bval[i].w);
        *(uint2*)(baseB + brow * 128 + (((bk4 >> 1) ^ (brow & 7)) << 4) + ((bk4 & 1) << 3)) = o;
      }
      __syncthreads();   // tile visible
      // ---- MFMA: 2 k-halves, 4x4 fragments each
#pragma unroll
      for (int kh = 0; kh < 2; ++kh) {
        bf16x8 af[4], bfr[4];
#pragma unroll
        for (int mi = 0; mi < 4; ++mi)
          af[mi] = *(const bf16x8*)(baseA + rowA[mi] * 128 +
                                    ((((kh << 2) | lg) ^ (rowA[mi] & 7)) << 4));
#pragma unroll
        for (int ni = 0; ni < 4; ++ni)
          bfr[ni] = *(const bf16x8*)(baseB + colB[ni] * 128 +
                                     ((((kh << 2) | lg) ^ (colB[ni] & 7)) << 4));
#pragma unroll
        for (int mi = 0; mi < 4; ++mi)
#pragma unroll
          for (int ni = 0; ni < 4; ++ni)
            acc[mi][ni] = __builtin_amdgcn_mfma_f32_16x16x32_bf16(
                af[mi], bfr[ni], acc[mi][ni], 0, 0, 0);
      }
    }

    // ---- per-row max & sumexp over this 128-col tile, online update.
    // D layout (verified): row = (lane>>4)*4 + reg, col = lane&15.
#pragma unroll
    for (int mi = 0; mi < 4; ++mi) {
#pragma unroll
      for (int r = 0; r < 4; ++r) {
        float m = acc[mi][0][r];
        m = fmaxf(m, acc[mi][1][r]);
        m = fmaxf(m, acc[mi][2][r]);
        m = fmaxf(m, acc[mi][3][r]);
#pragma unroll
        for (int d = 1; d < 16; d <<= 1) m = fmaxf(m, __shfl_xor(m, d, 64));
        float s = __expf(acc[mi][0][r] - m) + __expf(acc[mi][1][r] - m) +
                  __expf(acc[mi][2][r] - m) + __expf(acc[mi][3][r] - m);
#pragma unroll
        for (int d = 1; d < 16; d <<= 1) s += __shfl_xor(s, d, 64);
        float om = rmax[mi][r];
        float nm = fmaxf(om, m);
        rsum[mi][r] = rsum[mi][r] * __expf(om - nm) + s * __expf(m - nm);
        rmax[mi][r] = nm;
      }
    }
  }

  // ---- write partials: one per (token, slice, wn-half)
  if (lr == 0) {
    int s2 = slice * 2 + wn;
#pragma unroll
    for (int mi = 0; mi < 4; ++mi)
#pragma unroll
      for (int r = 0; r < 4; ++r) {
        int rowg = mrow0 + wm * 64 + mi * 16 + lg * 4 + r;
        partials[(size_t)s2 * TOKENS + rowg] = make_float2(rmax[mi][r], rsum[mi][r]);
      }
  }
}

// ---------------------------------------------------------------- combine partials
__global__ void k_reduce(const float2* __restrict__ partials,
                         const float* __restrict__ tgt,
                         const int* __restrict__ tg,
                         float* __restrict__ loss) {
  int tok = blockIdx.x * 256 + threadIdx.x;
  int m64 = tgt_mode64(tg);
  float m = -INFINITY, s = 0.f;
  for (int p = 0; p < NPART; ++p) {
    float2 v = partials[(size_t)p * TOKENS + tok];
    float nm = fmaxf(m, v.x);
    s = s * __expf(m - nm) + v.y * __expf(v.x - nm);
    m = nm;
  }
  int t = load_tgt(tg, tok, m64);
  float valid = (t != IGNORE_IDX) ? 1.f : 0.f;
  loss[tok] = (m + __logf(s) - tgt[tok]) * valid;
}

// ---------------------------------------------------------------- final mean
__global__ void k_final(const float* __restrict__ loss, const int* __restrict__ tg,
                        float* __restrict__ out) {
  __shared__ float ssum[256];
  __shared__ int scnt[256];
  int m64 = tgt_mode64(tg);
  float s = 0.f; int c = 0;
  for (int tok = threadIdx.x; tok < TOKENS; tok += 256) {
    s += loss[tok];
    c += (load_tgt(tg, tok, m64) != IGNORE_IDX) ? 1 : 0;
  }
  ssum[threadIdx.x] = s; scnt[threadIdx.x] = c;
  __syncthreads();
  for (int d = 128; d > 0; d >>= 1) {
    if (threadIdx.x < d) { ssum[threadIdx.x] += ssum[threadIdx.x + d];
                           scnt[threadIdx.x] += scnt[threadIdx.x + d]; }
    __syncthreads();
  }
  if (threadIdx.x == 0) out[0] = ssum[0] / (float)max(scnt[0], 1);
}

// ---------------------------------------------------------------- launch
extern "C" void kernel_launch(void* const* d_in, const int* in_sizes, int n_in,
                              void* d_out, int out_size, void* d_ws, size_t ws_size,
                              hipStream_t stream) {
  const float* H = (const float*)d_in[0];
  const float* W = (const float*)d_in[1];
  const int* tg = (const int*)d_in[2];
  float* out = (float*)d_out;

  char* ws = (char*)d_ws;
  uint16_t* Hb = (uint16_t*)ws;                                   // 16 MB
  float2* partials = (float2*)(ws + (size_t)TOKENS * DMODEL * 2); // 2 MB
  float* tgt = (float*)((char*)partials + (size_t)NPART * TOKENS * sizeof(float2));
  float* loss = tgt + TOKENS;

  k_convert<<<512, 256, 0, stream>>>(H, (uint32_t*)Hb);
  k_tgt<<<TOKENS / 4, 256, 0, stream>>>(H, W, tg, tgt);
  k_gemm<<<32 * NSPLIT, 256, 0, stream>>>(Hb, W, partials);
  k_reduce<<<TOKENS / 256, 256, 0, stream>>>(partials, tgt, tg, loss);
  k_final<<<1, 256, 0, stream>>>(loss, tg, out);
}